// Round 10
// baseline (48.454 us; speedup 1.0000x reference)
//
#include <hip/hip_runtime.h>
#include <math.h>

#define IH 512
#define IW 512
#define NPX (IH*IW)

// column-D + shuffle-box geometry
#define TW 60                // output columns per tile (64 lanes -> D cols -2..61)
#define BH 16                // tile height (4 waves x 4 rows)
#define NXT 9                // ceil(512/60)
#define YROWS 30             // image rows -7..22
#define YCOLS 74             // image cols -7..66
#define YSZ2 (YROWS*YCOLS)   // 2220
#define RROWS 26             // rows -5..20
#define RCOLS 74             // cols -5..68
#define RCH2 (RROWS*RCOLS)   // 1924

// mono-fallback geometry (round-5 kernel)
#define TS 32
#define YHALO 7
#define RHALO 5
#define YD (TS + 2*YHALO)
#define RD (TS + 2*RHALO)
#define RSZ (RD*RD)
#define MYSZ (YD*YD)

#define FSQRT(x) __builtin_amdgcn_sqrtf(x)
#if __has_builtin(__builtin_amdgcn_exp2f)
#define FEXP2(x) __builtin_amdgcn_exp2f(x)
#else
#define FEXP2(x) exp2f(x)
#endif

// lane shuffle: pull value from lane (addr>>2)&63 -- register-only crossbar
__device__ __forceinline__ float shf(float v, int addr) {
    return __int_as_float(__builtin_amdgcn_ds_bpermute(addr, __float_as_int(v)));
}

// ---------------- column-D compute kernel: dx-group per blockIdx.z -----------
// Round-9 post-mortem: LDS-pipe bound at ~25 DS ops/wave-shift. This version
// cuts to 14: the 12 per-shift RGB ds_reads become a rolling 4-row float4
// register window (RGB packed R,G,B,pad in LDS; rows slide by 1 per k, so
// 1 ds_read_b128 per shift + 4 init reads per dx). All window indices are
// compile-time (k unrolled). 12 ds_bpermute for the 5-col horizontal box.
// NO min-waves clamp (round-2: (256,4) forced VGPR=64 -> 0.5GB spill).
__global__ __launch_bounds__(256)
void nlm_part(const float* __restrict__ rgb,
              const float* __restrict__ sigma,
              float4* __restrict__ ws) {
    __shared__ float  YL[YSZ2];
    __shared__ float4 RGBL4[RCH2];

    const int tid   = threadIdx.x;
    const int lane  = tid & 63;
    const int wavei = tid >> 6;
    const int tx0 = blockIdx.x * TW;
    const int ty0 = blockIdx.y * BH;
    const int slice = blockIdx.z;
    const int nz = gridDim.z;

    const float* Rp = rgb;
    const float* Gp = rgb + NPX;
    const float* Bp = rgb + 2*NPX;

    // stage luminance: rows -7..22, cols -7..66 (circular)
    for (int idx = tid; idx < YSZ2; idx += 256) {
        int a = idx / YCOLS, b = idx - a*YCOLS;
        int gy = (ty0 + a - 7) & (IH-1);
        int gx = (tx0 + b - 7) & (IW-1);
        int g = gy*IW + gx;
        YL[idx] = 0.299f*Rp[g] + 0.587f*Gp[g] + 0.114f*Bp[g];
    }
    // stage RGB packed float4: rows -5..20, cols -5..68 (circular)
    for (int idx = tid; idx < RCH2; idx += 256) {
        int a = idx / RCOLS, b = idx - a*RCOLS;
        int gy = (ty0 + a - 5) & (IH-1);
        int gx = (tx0 + b - 5) & (IW-1);
        int g = gy*IW + gx;
        RGBL4[idx] = make_float4(Rp[g], Gp[g], Bp[g], 0.f);
    }
    __syncthreads();

    const float m2 = -1.4426950408889634f /
                     (fmaxf(sigma[0]*2.0f, 0.0f) + 1e-6f);

    const int l  = lane;         // D col cd = l-2; output col = l (<60)
    const int r0 = wavei*4;      // strip start row

    // shuffle addresses (byte): source lanes l+1, l+2, l+4
    const int a1 = ((l + 1) & 63) << 2;
    const int a2 = ((l + 2) & 63) << 2;
    const int a4 = ((l + 4) & 63) << 2;

    // minuend Y at D col cd=l-2: rows r0-2..r0+5  (LDS: row r0+5+i, col l+5)
    float yb8[8];
    #pragma unroll
    for (int i = 0; i < 8; ++i)
        yb8[i] = YL[(r0+5+i)*YCOLS + (l+5)];

    float accR[4]={0,0,0,0}, accG[4]={0,0,0,0},
          accB[4]={0,0,0,0}, den[4]={0,0,0,0};

    int dxlo, dxcnt;
    if (nz == 6) { if (slice < 5) { dxlo = -5 + 2*slice; dxcnt = 2; }
                   else           { dxlo = 5;            dxcnt = 1; } }
    else         { if (slice < 3) { dxlo = -5 + 3*slice; dxcnt = 3; }
                   else           { dxlo = 4;            dxcnt = 2; } }

    for (int u = 0; u < dxcnt; ++u) {
        const int dx = dxlo + u;
        const int ysb   = r0*YCOLS + (l + 5 - dx);    // subtrahend col base
        const int rgb_b = r0*RCOLS + (l + 5 - dx);    // rgb col base (f4 elems)

        // rolling subtrahend rows: slot j holds storage row r0+j at k=0
        float sub8[8];
        #pragma unroll
        for (int j = 0; j < 8; ++j)
            sub8[j] = YL[ysb + j*YCOLS];

        // rolling RGB window: slot s holds storage row r0+s at k=0
        float4 rgbw[4];
        #pragma unroll
        for (int s = 0; s < 4; ++s)
            rgbw[s] = RGBL4[rgb_b + s*RCOLS];

        #pragma unroll
        for (int k = 0; k <= 10; ++k) {               // dy = 5 - k
            if (k > 0) {
                sub8[(k+7)&7] = YL[ysb + (7+k)*YCOLS];
                rgbw[(k+3)&3] = RGBL4[rgb_b + (k+3)*RCOLS];
            }
            // own-column E + vertical box via prefix (square folded into fma)
            float pre[9]; pre[0] = 0.f;
            #pragma unroll
            for (int i = 0; i < 8; ++i) {
                float d = yb8[i] - sub8[(i+k)&7];
                pre[i+1] = fmaf(d, d, pre[i]);
            }
            float V[4];
            #pragma unroll
            for (int rr = 0; rr < 4; ++rr) V[rr] = pre[rr+5] - pre[rr];

            // horizontal 5-col box: lanes l..l+4 via 3-ladder bpermute
            float box[4];
            #pragma unroll
            for (int rr = 0; rr < 4; ++rr) {
                float t1 = V[rr] + shf(V[rr], a1);
                float t2 = t1 + shf(t1, a2);
                box[rr] = t2 + shf(V[rr], a4);
            }
            #pragma unroll
            for (int rr = 0; rr < 4; ++rr) {
                float w = FEXP2(FSQRT(fmaxf(box[rr], 0.f)) * m2);
                float4 p = rgbw[(k+rr)&3];
                accR[rr] = fmaf(w, p.x, accR[rr]);
                accG[rr] = fmaf(w, p.y, accG[rr]);
                accB[rr] = fmaf(w, p.z, accB[rr]);
                den[rr] += w;
            }
        }
    }

    if (l < TW && tx0 + l < IW) {
        #pragma unroll
        for (int rr = 0; rr < 4; ++rr) {
            int px = (ty0 + r0 + rr)*IW + tx0 + l;
            ws[(size_t)slice*NPX + px] =
                make_float4(accR[rr], accG[rr], accB[rr], den[rr]);
        }
    }
}

// ---------------- combine: sum nslice slices, normalize, clip ----------------
__global__ __launch_bounds__(256)
void nlm_combine(const float4* __restrict__ ws, float* __restrict__ out,
                 int nslice) {
    int px = blockIdx.x * 256 + threadIdx.x;
    float r = 0.f, g = 0.f, b = 0.f, w = 0.f;
    for (int s = 0; s < nslice; ++s) {
        float4 v = ws[(size_t)s * NPX + px];
        r += v.x; g += v.y; b += v.z; w += v.w;
    }
    float iw = 1.0f / w;
    out[px]           = fminf(fmaxf(r * iw, 0.f), 1.f);
    out[NPX + px]     = fminf(fmaxf(g * iw, 0.f), 1.f);
    out[2 * NPX + px] = fminf(fmaxf(b * iw, 0.f), 1.f);
}

// ---------------- fallback: round-5 monolithic kernel (ws too small) ---------
__global__ __launch_bounds__(256)
void nlm_mono(const float* __restrict__ rgb,
              const float* __restrict__ sigma,
              float* __restrict__ out) {
    __shared__ float Y[MYSZ];
    __shared__ float RGBL[3 * RSZ];

    const int tid = threadIdx.x;
    const int tx0 = blockIdx.x * TS;
    const int ty0 = blockIdx.y * TS;

    const float* Rp = rgb;
    const float* Gp = rgb + NPX;
    const float* Bp = rgb + 2 * NPX;

    for (int idx = tid; idx < MYSZ; idx += 256) {
        int a = idx / YD, b = idx - a * YD;
        int gy = (ty0 + a - YHALO) & (IH - 1);
        int gx = (tx0 + b - YHALO) & (IW - 1);
        int g = gy * IW + gx;
        Y[idx] = 0.299f * Rp[g] + 0.587f * Gp[g] + 0.114f * Bp[g];
    }
    for (int idx = tid; idx < RSZ; idx += 256) {
        int a = idx / RD, b = idx - a * RD;
        int gy = (ty0 + a - RHALO) & (IH - 1);
        int gx = (tx0 + b - RHALO) & (IW - 1);
        int g = gy * IW + gx;
        RGBL[idx]           = Rp[g];
        RGBL[RSZ + idx]     = Gp[g];
        RGBL[2 * RSZ + idx] = Bp[g];
    }
    __syncthreads();

    const float minv_h = -1.0f / (fmaxf(sigma[0] * 2.0f, 0.0f) + 1e-6f);
    const int tx = tid & 31;
    const int tz = tid >> 5;
    const int r0 = tz * 4;

    const int ybase = (YHALO + r0 - 2) * YD + (YHALO + tx - 2);
    float yb[8][5];
    #pragma unroll
    for (int i = 0; i < 8; ++i)
        #pragma unroll
        for (int b = 0; b < 5; ++b)
            yb[i][b] = Y[ybase + i * YD + b];

    float accR[4] = {0.f,0.f,0.f,0.f}, accG[4] = {0.f,0.f,0.f,0.f};
    float accB[4] = {0.f,0.f,0.f,0.f}, den[4] = {0.f,0.f,0.f,0.f};

    for (int dx = -5; dx <= 5; ++dx) {
        const int ybd = (YHALO + r0 - 7) * YD + (YHALO + tx - 2 - dx);
        const int rbd = (RHALO + r0 - 5) * RD + (RHALO + tx - dx);

        #pragma unroll
        for (int k = 0; k <= 10; ++k) {
            float hs[8];
            #pragma unroll
            for (int i = 0; i < 8; ++i) {
                float s = 0.f;
                #pragma unroll
                for (int b = 0; b < 5; ++b) {
                    float d = yb[i][b] - Y[ybd + (i + k) * YD + b];
                    s = fmaf(d, d, s);
                }
                hs[i] = s;
            }
            float pre[9];
            pre[0] = 0.f;
            #pragma unroll
            for (int i = 0; i < 8; ++i) pre[i + 1] = pre[i] + hs[i];
            #pragma unroll
            for (int rr = 0; rr < 4; ++rr) {
                float box = pre[rr + 5] - pre[rr];
                float w = __expf(FSQRT(box) * minv_h);
                const int s2 = rbd + (rr + k) * RD;
                accR[rr] = fmaf(w, RGBL[s2], accR[rr]);
                accG[rr] = fmaf(w, RGBL[RSZ + s2], accG[rr]);
                accB[rr] = fmaf(w, RGBL[2 * RSZ + s2], accB[rr]);
                den[rr] += w;
            }
        }
    }

    #pragma unroll
    for (int rr = 0; rr < 4; ++rr) {
        int px = (ty0 + r0 + rr) * IW + tx0 + tx;
        float iw = 1.0f / den[rr];
        out[px]           = fminf(fmaxf(accR[rr] * iw, 0.f), 1.f);
        out[NPX + px]     = fminf(fmaxf(accG[rr] * iw, 0.f), 1.f);
        out[2 * NPX + px] = fminf(fmaxf(accB[rr] * iw, 0.f), 1.f);
    }
}

extern "C" void kernel_launch(void* const* d_in, const int* in_sizes, int n_in,
                              void* d_out, int out_size, void* d_ws, size_t ws_size,
                              hipStream_t stream) {
    const float* rgb   = (const float*)d_in[0];
    const float* sigma = (const float*)d_in[1];
    float* out = (float*)d_out;

    const size_t need6 = (size_t)6 * NPX * sizeof(float4);
    const size_t need4 = (size_t)4 * NPX * sizeof(float4);
    int nslice = (ws_size >= need6) ? 6 : (ws_size >= need4 ? 4 : 0);

    if (nslice > 0) {
        float4* ws = (float4*)d_ws;
        dim3 grid(NXT, IH / BH, nslice);   // 9 x 32 x {6|4}
        nlm_part<<<grid, dim3(256), 0, stream>>>(rgb, sigma, ws);
        nlm_combine<<<dim3(NPX / 256), dim3(256), 0, stream>>>(ws, out, nslice);
    } else {
        dim3 grid(IW / TS, IH / TS);
        nlm_mono<<<grid, dim3(256), 0, stream>>>(rgb, sigma, out);
    }
}

// Round 11
// 41.901 us; speedup vs baseline: 1.1564x; 1.1564x over previous
//
#include <hip/hip_runtime.h>
#include <math.h>

#define IH 512
#define IW 512
#define NPX (IH*IW)

// column-D + dpp-shift-box geometry
#define TW 60                // output columns per tile (64 lanes -> D cols -2..61)
#define BH 16                // tile height (4 waves x 4 rows)
#define NXT 9                // ceil(512/60)
#define YROWS 30             // image rows -7..22
#define YCOLS 74             // image cols -7..66
#define YSZ2 (YROWS*YCOLS)   // 2220
#define RROWS 26             // rows -5..20
#define RCOLS 74             // cols -5..68
#define RCH2 (RROWS*RCOLS)   // 1924

// mono-fallback geometry (round-5 kernel)
#define TS 32
#define YHALO 7
#define RHALO 5
#define YD (TS + 2*YHALO)
#define RD (TS + 2*RHALO)
#define RSZ (RD*RD)
#define MYSZ (YD*YD)

#define FSQRT(x) __builtin_amdgcn_sqrtf(x)
#if __has_builtin(__builtin_amdgcn_exp2f)
#define FEXP2(x) __builtin_amdgcn_exp2f(x)
#else
#define FEXP2(x) exp2f(x)
#endif

// DPP wave_shl:1 (ctrl 0x130): lane i <- lane i+1, whole-wave, lane63 <- 0.
// VALU-pipe lane shift: replaces the serial ds_bpermute ladder (round-10
// post-mortem: 12 high-latency DS ops/shift were the stall, not throughput).
__device__ __forceinline__ float dpp_shl1(float x) {
    return __int_as_float(__builtin_amdgcn_update_dpp(
        0, __float_as_int(x), 0x130, 0xf, 0xf, true));
}

// ---------------- column-D compute kernel: dx-group per blockIdx.z -----------
// Wave = 64 D-columns (cols -2..61 of a 60-wide output tile). Per shift each
// lane: 1 rolling Y ds_read_b32 + 1 rolling RGB ds_read_b128 (only DS ops),
// 8 sub+8 fma prefix -> V[4] vertical box, horizontal 5-col box via 4 chained
// dpp wave_shl:1 + tree adds per component (VALU), 4x sqrt/exp2, 16 fma.
// NO min-waves clamp (round-2: (256,4) forced VGPR=64 -> 0.5GB spill).
__global__ __launch_bounds__(256)
void nlm_part(const float* __restrict__ rgb,
              const float* __restrict__ sigma,
              float4* __restrict__ ws) {
    __shared__ float  YL[YSZ2];
    __shared__ float4 RGBL4[RCH2];

    const int tid   = threadIdx.x;
    const int lane  = tid & 63;
    const int wavei = tid >> 6;
    const int tx0 = blockIdx.x * TW;
    const int ty0 = blockIdx.y * BH;
    const int slice = blockIdx.z;
    const int nz = gridDim.z;

    const float* Rp = rgb;
    const float* Gp = rgb + NPX;
    const float* Bp = rgb + 2*NPX;

    // stage luminance: rows -7..22, cols -7..66 (circular)
    for (int idx = tid; idx < YSZ2; idx += 256) {
        int a = idx / YCOLS, b = idx - a*YCOLS;
        int gy = (ty0 + a - 7) & (IH-1);
        int gx = (tx0 + b - 7) & (IW-1);
        int g = gy*IW + gx;
        YL[idx] = 0.299f*Rp[g] + 0.587f*Gp[g] + 0.114f*Bp[g];
    }
    // stage RGB packed float4: rows -5..20, cols -5..68 (circular)
    for (int idx = tid; idx < RCH2; idx += 256) {
        int a = idx / RCOLS, b = idx - a*RCOLS;
        int gy = (ty0 + a - 5) & (IH-1);
        int gx = (tx0 + b - 5) & (IW-1);
        int g = gy*IW + gx;
        RGBL4[idx] = make_float4(Rp[g], Gp[g], Bp[g], 0.f);
    }
    __syncthreads();

    const float m2 = -1.4426950408889634f /
                     (fmaxf(sigma[0]*2.0f, 0.0f) + 1e-6f);

    const int l  = lane;         // D col cd = l-2; output col = l (<60)
    const int r0 = wavei*4;      // strip start row

    // minuend Y at D col cd=l-2: rows r0-2..r0+5  (LDS: row r0+5+i, col l+5)
    float yb8[8];
    #pragma unroll
    for (int i = 0; i < 8; ++i)
        yb8[i] = YL[(r0+5+i)*YCOLS + (l+5)];

    float accR[4]={0,0,0,0}, accG[4]={0,0,0,0},
          accB[4]={0,0,0,0}, den[4]={0,0,0,0};

    int dxlo, dxcnt;
    if (nz == 6) { if (slice < 5) { dxlo = -5 + 2*slice; dxcnt = 2; }
                   else           { dxlo = 5;            dxcnt = 1; } }
    else         { if (slice < 3) { dxlo = -5 + 3*slice; dxcnt = 3; }
                   else           { dxlo = 4;            dxcnt = 2; } }

    for (int u = 0; u < dxcnt; ++u) {
        const int dx = dxlo + u;
        const int ysb   = r0*YCOLS + (l + 5 - dx);    // subtrahend col base
        const int rgb_b = r0*RCOLS + (l + 5 - dx);    // rgb col base (f4 elems)

        // rolling subtrahend rows: slot j holds storage row r0+j at k=0
        float sub8[8];
        #pragma unroll
        for (int j = 0; j < 8; ++j)
            sub8[j] = YL[ysb + j*YCOLS];

        // rolling RGB window: slot s holds storage row r0+s at k=0
        float4 rgbw[4];
        #pragma unroll
        for (int s = 0; s < 4; ++s)
            rgbw[s] = RGBL4[rgb_b + s*RCOLS];

        #pragma unroll
        for (int k = 0; k <= 10; ++k) {               // dy = 5 - k
            if (k > 0) {
                sub8[(k+7)&7] = YL[ysb + (7+k)*YCOLS];
                rgbw[(k+3)&3] = RGBL4[rgb_b + (k+3)*RCOLS];
            }
            // own-column E + vertical box via prefix (square folded into fma)
            float pre[9]; pre[0] = 0.f;
            #pragma unroll
            for (int i = 0; i < 8; ++i) {
                float d = yb8[i] - sub8[(i+k)&7];
                pre[i+1] = fmaf(d, d, pre[i]);
            }
            float V[4];
            #pragma unroll
            for (int rr = 0; rr < 4; ++rr) V[rr] = pre[rr+5] - pre[rr];

            // horizontal 5-col box over lanes l..l+4 via chained dpp shifts
            float box[4];
            #pragma unroll
            for (int rr = 0; rr < 4; ++rr) {
                float s1 = dpp_shl1(V[rr]);           // V[l+1]
                float s2 = dpp_shl1(s1);              // V[l+2]
                float s3 = dpp_shl1(s2);              // V[l+3]
                float s4 = dpp_shl1(s3);              // V[l+4]
                box[rr] = ((V[rr] + s1) + (s2 + s3)) + s4;
            }
            #pragma unroll
            for (int rr = 0; rr < 4; ++rr) {
                float w = FEXP2(FSQRT(fmaxf(box[rr], 0.f)) * m2);
                float4 p = rgbw[(k+rr)&3];
                accR[rr] = fmaf(w, p.x, accR[rr]);
                accG[rr] = fmaf(w, p.y, accG[rr]);
                accB[rr] = fmaf(w, p.z, accB[rr]);
                den[rr] += w;
            }
        }
    }

    if (l < TW && tx0 + l < IW) {
        #pragma unroll
        for (int rr = 0; rr < 4; ++rr) {
            int px = (ty0 + r0 + rr)*IW + tx0 + l;
            ws[(size_t)slice*NPX + px] =
                make_float4(accR[rr], accG[rr], accB[rr], den[rr]);
        }
    }
}

// ---------------- combine: sum nslice slices, normalize, clip ----------------
__global__ __launch_bounds__(256)
void nlm_combine(const float4* __restrict__ ws, float* __restrict__ out,
                 int nslice) {
    int px = blockIdx.x * 256 + threadIdx.x;
    float r = 0.f, g = 0.f, b = 0.f, w = 0.f;
    for (int s = 0; s < nslice; ++s) {
        float4 v = ws[(size_t)s * NPX + px];
        r += v.x; g += v.y; b += v.z; w += v.w;
    }
    float iw = 1.0f / w;
    out[px]           = fminf(fmaxf(r * iw, 0.f), 1.f);
    out[NPX + px]     = fminf(fmaxf(g * iw, 0.f), 1.f);
    out[2 * NPX + px] = fminf(fmaxf(b * iw, 0.f), 1.f);
}

// ---------------- fallback: round-5 monolithic kernel (ws too small) ---------
__global__ __launch_bounds__(256)
void nlm_mono(const float* __restrict__ rgb,
              const float* __restrict__ sigma,
              float* __restrict__ out) {
    __shared__ float Y[MYSZ];
    __shared__ float RGBL[3 * RSZ];

    const int tid = threadIdx.x;
    const int tx0 = blockIdx.x * TS;
    const int ty0 = blockIdx.y * TS;

    const float* Rp = rgb;
    const float* Gp = rgb + NPX;
    const float* Bp = rgb + 2 * NPX;

    for (int idx = tid; idx < MYSZ; idx += 256) {
        int a = idx / YD, b = idx - a * YD;
        int gy = (ty0 + a - YHALO) & (IH - 1);
        int gx = (tx0 + b - YHALO) & (IW - 1);
        int g = gy * IW + gx;
        Y[idx] = 0.299f * Rp[g] + 0.587f * Gp[g] + 0.114f * Bp[g];
    }
    for (int idx = tid; idx < RSZ; idx += 256) {
        int a = idx / RD, b = idx - a * RD;
        int gy = (ty0 + a - RHALO) & (IH - 1);
        int gx = (tx0 + b - RHALO) & (IW - 1);
        int g = gy * IW + gx;
        RGBL[idx]           = Rp[g];
        RGBL[RSZ + idx]     = Gp[g];
        RGBL[2 * RSZ + idx] = Bp[g];
    }
    __syncthreads();

    const float minv_h = -1.0f / (fmaxf(sigma[0] * 2.0f, 0.0f) + 1e-6f);
    const int tx = tid & 31;
    const int tz = tid >> 5;
    const int r0 = tz * 4;

    const int ybase = (YHALO + r0 - 2) * YD + (YHALO + tx - 2);
    float yb[8][5];
    #pragma unroll
    for (int i = 0; i < 8; ++i)
        #pragma unroll
        for (int b = 0; b < 5; ++b)
            yb[i][b] = Y[ybase + i * YD + b];

    float accR[4] = {0.f,0.f,0.f,0.f}, accG[4] = {0.f,0.f,0.f,0.f};
    float accB[4] = {0.f,0.f,0.f,0.f}, den[4] = {0.f,0.f,0.f,0.f};

    for (int dx = -5; dx <= 5; ++dx) {
        const int ybd = (YHALO + r0 - 7) * YD + (YHALO + tx - 2 - dx);
        const int rbd = (RHALO + r0 - 5) * RD + (RHALO + tx - dx);

        #pragma unroll
        for (int k = 0; k <= 10; ++k) {
            float hs[8];
            #pragma unroll
            for (int i = 0; i < 8; ++i) {
                float s = 0.f;
                #pragma unroll
                for (int b = 0; b < 5; ++b) {
                    float d = yb[i][b] - Y[ybd + (i + k) * YD + b];
                    s = fmaf(d, d, s);
                }
                hs[i] = s;
            }
            float pre[9];
            pre[0] = 0.f;
            #pragma unroll
            for (int i = 0; i < 8; ++i) pre[i + 1] = pre[i] + hs[i];
            #pragma unroll
            for (int rr = 0; rr < 4; ++rr) {
                float box = pre[rr + 5] - pre[rr];
                float w = __expf(FSQRT(box) * minv_h);
                const int s2 = rbd + (rr + k) * RD;
                accR[rr] = fmaf(w, RGBL[s2], accR[rr]);
                accG[rr] = fmaf(w, RGBL[RSZ + s2], accG[rr]);
                accB[rr] = fmaf(w, RGBL[2 * RSZ + s2], accB[rr]);
                den[rr] += w;
            }
        }
    }

    #pragma unroll
    for (int rr = 0; rr < 4; ++rr) {
        int px = (ty0 + r0 + rr) * IW + tx0 + tx;
        float iw = 1.0f / den[rr];
        out[px]           = fminf(fmaxf(accR[rr] * iw, 0.f), 1.f);
        out[NPX + px]     = fminf(fmaxf(accG[rr] * iw, 0.f), 1.f);
        out[2 * NPX + px] = fminf(fmaxf(accB[rr] * iw, 0.f), 1.f);
    }
}

extern "C" void kernel_launch(void* const* d_in, const int* in_sizes, int n_in,
                              void* d_out, int out_size, void* d_ws, size_t ws_size,
                              hipStream_t stream) {
    const float* rgb   = (const float*)d_in[0];
    const float* sigma = (const float*)d_in[1];
    float* out = (float*)d_out;

    const size_t need6 = (size_t)6 * NPX * sizeof(float4);
    const size_t need4 = (size_t)4 * NPX * sizeof(float4);
    int nslice = (ws_size >= need6) ? 6 : (ws_size >= need4 ? 4 : 0);

    if (nslice > 0) {
        float4* ws = (float4*)d_ws;
        dim3 grid(NXT, IH / BH, nslice);   // 9 x 32 x {6|4}
        nlm_part<<<grid, dim3(256), 0, stream>>>(rgb, sigma, ws);
        nlm_combine<<<dim3(NPX / 256), dim3(256), 0, stream>>>(ws, out, nslice);
    } else {
        dim3 grid(IW / TS, IH / TS);
        nlm_mono<<<grid, dim3(256), 0, stream>>>(rgb, sigma, out);
    }
}

// Round 12
// 41.665 us; speedup vs baseline: 1.1629x; 1.0057x over previous
//
#include <hip/hip_runtime.h>
#include <math.h>

#define IH 512
#define IW 512
#define NPX (IH*IW)

// column-D + dpp-shift-box geometry
#define TW 60                // output columns per tile (64 lanes -> D cols -2..61)
#define BH 16                // tile height (4 waves x 4 rows)
#define NXT 9                // ceil(512/60)
#define YROWS 30             // image rows -7..22
#define YCOLS 74             // image cols -7..66
#define YSZ2 (YROWS*YCOLS)   // 2220
#define RROWS 26             // rows -5..20
#define RCOLS 74             // cols -5..68
#define RCH2 (RROWS*RCOLS)   // 1924

// mono-fallback geometry (round-5 kernel)
#define TS 32
#define YHALO 7
#define RHALO 5
#define YD (TS + 2*YHALO)
#define RD (TS + 2*RHALO)
#define RSZ (RD*RD)
#define MYSZ (YD*YD)

#define FSQRT(x) __builtin_amdgcn_sqrtf(x)
#if __has_builtin(__builtin_amdgcn_exp2f)
#define FEXP2(x) __builtin_amdgcn_exp2f(x)
#else
#define FEXP2(x) exp2f(x)
#endif

// DPP wave_shl:1 (ctrl 0x130): lane i <- lane i+1, whole-wave, lane63 <- 0.
__device__ __forceinline__ float dpp_shl1(float x) {
    return __int_as_float(__builtin_amdgcn_update_dpp(
        0, __float_as_int(x), 0x130, 0xf, 0xf, true));
}

// ---------------- column-D compute kernel: dx-group per blockIdx.z -----------
// Round-11 post-mortem: rolling ds_reads had ZERO slack (row loaded at k is
// consumed by k's prefix) -> ~120cy LDS latency on the critical path each
// iteration, unhidden at ~2 waves/SIMD. This version:
// (a) explicit 1-iteration prefetch (nY/nRG/nB temps: load at k, consume k+1),
// (b) RGB split into float2 RG + float B planes -> LDS 31.97KB -> 5 blocks/CU
//     (was 39.9KB -> 4); DS ops 2->3/shift is fine (round-10: throughput slack).
// NO min-waves clamp (round-2: (256,4) forced VGPR=64 -> 0.5GB spill).
__global__ __launch_bounds__(256)
void nlm_part(const float* __restrict__ rgb,
              const float* __restrict__ sigma,
              float4* __restrict__ ws) {
    __shared__ float  YL[YSZ2];      //  8880 B
    __shared__ float2 RGL[RCH2];     // 15392 B
    __shared__ float  BL[RCH2];      //  7696 B   total 31968 B

    const int tid   = threadIdx.x;
    const int lane  = tid & 63;
    const int wavei = tid >> 6;
    const int tx0 = blockIdx.x * TW;
    const int ty0 = blockIdx.y * BH;
    const int slice = blockIdx.z;
    const int nz = gridDim.z;

    const float* Rp = rgb;
    const float* Gp = rgb + NPX;
    const float* Bp = rgb + 2*NPX;

    // stage luminance: rows -7..22, cols -7..66 (circular)
    for (int idx = tid; idx < YSZ2; idx += 256) {
        int a = idx / YCOLS, b = idx - a*YCOLS;
        int gy = (ty0 + a - 7) & (IH-1);
        int gx = (tx0 + b - 7) & (IW-1);
        int g = gy*IW + gx;
        YL[idx] = 0.299f*Rp[g] + 0.587f*Gp[g] + 0.114f*Bp[g];
    }
    // stage RGB planes: rows -5..20, cols -5..68 (circular)
    for (int idx = tid; idx < RCH2; idx += 256) {
        int a = idx / RCOLS, b = idx - a*RCOLS;
        int gy = (ty0 + a - 5) & (IH-1);
        int gx = (tx0 + b - 5) & (IW-1);
        int g = gy*IW + gx;
        RGL[idx] = make_float2(Rp[g], Gp[g]);
        BL[idx]  = Bp[g];
    }
    __syncthreads();

    const float m2 = -1.4426950408889634f /
                     (fmaxf(sigma[0]*2.0f, 0.0f) + 1e-6f);

    const int l  = lane;         // D col cd = l-2; output col = l (<60)
    const int r0 = wavei*4;      // strip start row

    // minuend Y at D col cd=l-2: rows r0-2..r0+5  (LDS: row r0+5+i, col l+5)
    float yb8[8];
    #pragma unroll
    for (int i = 0; i < 8; ++i)
        yb8[i] = YL[(r0+5+i)*YCOLS + (l+5)];

    float accR[4]={0,0,0,0}, accG[4]={0,0,0,0},
          accB[4]={0,0,0,0}, den[4]={0,0,0,0};

    int dxlo, dxcnt;
    if (nz == 6) { if (slice < 5) { dxlo = -5 + 2*slice; dxcnt = 2; }
                   else           { dxlo = 5;            dxcnt = 1; } }
    else         { if (slice < 3) { dxlo = -5 + 3*slice; dxcnt = 3; }
                   else           { dxlo = 4;            dxcnt = 2; } }

    for (int u = 0; u < dxcnt; ++u) {
        const int dx = dxlo + u;
        const int ysb   = r0*YCOLS + (l + 5 - dx);    // subtrahend col base
        const int rgb_b = r0*RCOLS + (l + 5 - dx);    // rgb col base

        // rolling subtrahend rows: slot j holds storage row j at k=0
        float sub8[8];
        #pragma unroll
        for (int j = 0; j < 8; ++j)
            sub8[j] = YL[ysb + j*YCOLS];

        // rolling RGB window: slot s holds storage row s at k=0
        float2 rgw[4];
        float  bw[4];
        #pragma unroll
        for (int s = 0; s < 4; ++s) {
            rgw[s] = RGL[rgb_b + s*RCOLS];
            bw[s]  = BL [rgb_b + s*RCOLS];
        }

        // prefetch temps: hold row 8 (Y) and row 4 (RGB) entering k=1
        float  nY  = YL [ysb   + 8*YCOLS];
        float2 nRG = RGL[rgb_b + 4*RCOLS];
        float  nB  = BL [rgb_b + 4*RCOLS];

        #pragma unroll
        for (int k = 0; k <= 10; ++k) {               // dy = 5 - k
            if (k > 0) {
                // consume prefetched rows (register moves, no latency)
                sub8[(k+7)&7] = nY;                   // Y row k+7
                rgw [(k+3)&3] = nRG;                  // RGB row k+3
                bw  [(k+3)&3] = nB;
                if (k < 10) {
                    // issue next loads; consumed at k+1 (full iter of slack)
                    nY  = YL [ysb   + (8+k)*YCOLS];
                    nRG = RGL[rgb_b + (4+k)*RCOLS];
                    nB  = BL [rgb_b + (4+k)*RCOLS];
                }
            }
            // own-column E + vertical box via prefix (square folded into fma)
            float pre[9]; pre[0] = 0.f;
            #pragma unroll
            for (int i = 0; i < 8; ++i) {
                float d = yb8[i] - sub8[(i+k)&7];
                pre[i+1] = fmaf(d, d, pre[i]);
            }
            float V[4];
            #pragma unroll
            for (int rr = 0; rr < 4; ++rr) V[rr] = pre[rr+5] - pre[rr];

            // horizontal 5-col box over lanes l..l+4 via chained dpp shifts
            float box[4];
            #pragma unroll
            for (int rr = 0; rr < 4; ++rr) {
                float s1 = dpp_shl1(V[rr]);           // V[l+1]
                float s2 = dpp_shl1(s1);              // V[l+2]
                float s3 = dpp_shl1(s2);              // V[l+3]
                float s4 = dpp_shl1(s3);              // V[l+4]
                box[rr] = ((V[rr] + s1) + (s2 + s3)) + s4;
            }
            #pragma unroll
            for (int rr = 0; rr < 4; ++rr) {
                float w = FEXP2(FSQRT(fmaxf(box[rr], 0.f)) * m2);
                float2 rg = rgw[(k+rr)&3];
                accR[rr] = fmaf(w, rg.x, accR[rr]);
                accG[rr] = fmaf(w, rg.y, accG[rr]);
                accB[rr] = fmaf(w, bw[(k+rr)&3], accB[rr]);
                den[rr] += w;
            }
        }
    }

    if (l < TW && tx0 + l < IW) {
        #pragma unroll
        for (int rr = 0; rr < 4; ++rr) {
            int px = (ty0 + r0 + rr)*IW + tx0 + l;
            ws[(size_t)slice*NPX + px] =
                make_float4(accR[rr], accG[rr], accB[rr], den[rr]);
        }
    }
}

// ---------------- combine: sum nslice slices, normalize, clip ----------------
__global__ __launch_bounds__(256)
void nlm_combine(const float4* __restrict__ ws, float* __restrict__ out,
                 int nslice) {
    int px = blockIdx.x * 256 + threadIdx.x;
    float r = 0.f, g = 0.f, b = 0.f, w = 0.f;
    for (int s = 0; s < nslice; ++s) {
        float4 v = ws[(size_t)s * NPX + px];
        r += v.x; g += v.y; b += v.z; w += v.w;
    }
    float iw = 1.0f / w;
    out[px]           = fminf(fmaxf(r * iw, 0.f), 1.f);
    out[NPX + px]     = fminf(fmaxf(g * iw, 0.f), 1.f);
    out[2 * NPX + px] = fminf(fmaxf(b * iw, 0.f), 1.f);
}

// ---------------- fallback: round-5 monolithic kernel (ws too small) ---------
__global__ __launch_bounds__(256)
void nlm_mono(const float* __restrict__ rgb,
              const float* __restrict__ sigma,
              float* __restrict__ out) {
    __shared__ float Y[MYSZ];
    __shared__ float RGBL[3 * RSZ];

    const int tid = threadIdx.x;
    const int tx0 = blockIdx.x * TS;
    const int ty0 = blockIdx.y * TS;

    const float* Rp = rgb;
    const float* Gp = rgb + NPX;
    const float* Bp = rgb + 2 * NPX;

    for (int idx = tid; idx < MYSZ; idx += 256) {
        int a = idx / YD, b = idx - a * YD;
        int gy = (ty0 + a - YHALO) & (IH - 1);
        int gx = (tx0 + b - YHALO) & (IW - 1);
        int g = gy * IW + gx;
        Y[idx] = 0.299f * Rp[g] + 0.587f * Gp[g] + 0.114f * Bp[g];
    }
    for (int idx = tid; idx < RSZ; idx += 256) {
        int a = idx / RD, b = idx - a * RD;
        int gy = (ty0 + a - RHALO) & (IH - 1);
        int gx = (tx0 + b - RHALO) & (IW - 1);
        int g = gy * IW + gx;
        RGBL[idx]           = Rp[g];
        RGBL[RSZ + idx]     = Gp[g];
        RGBL[2 * RSZ + idx] = Bp[g];
    }
    __syncthreads();

    const float minv_h = -1.0f / (fmaxf(sigma[0] * 2.0f, 0.0f) + 1e-6f);
    const int tx = tid & 31;
    const int tz = tid >> 5;
    const int r0 = tz * 4;

    const int ybase = (YHALO + r0 - 2) * YD + (YHALO + tx - 2);
    float yb[8][5];
    #pragma unroll
    for (int i = 0; i < 8; ++i)
        #pragma unroll
        for (int b = 0; b < 5; ++b)
            yb[i][b] = Y[ybase + i * YD + b];

    float accR[4] = {0.f,0.f,0.f,0.f}, accG[4] = {0.f,0.f,0.f,0.f};
    float accB[4] = {0.f,0.f,0.f,0.f}, den[4] = {0.f,0.f,0.f,0.f};

    for (int dx = -5; dx <= 5; ++dx) {
        const int ybd = (YHALO + r0 - 7) * YD + (YHALO + tx - 2 - dx);
        const int rbd = (RHALO + r0 - 5) * RD + (RHALO + tx - dx);

        #pragma unroll
        for (int k = 0; k <= 10; ++k) {
            float hs[8];
            #pragma unroll
            for (int i = 0; i < 8; ++i) {
                float s = 0.f;
                #pragma unroll
                for (int b = 0; b < 5; ++b) {
                    float d = yb[i][b] - Y[ybd + (i + k) * YD + b];
                    s = fmaf(d, d, s);
                }
                hs[i] = s;
            }
            float pre[9];
            pre[0] = 0.f;
            #pragma unroll
            for (int i = 0; i < 8; ++i) pre[i + 1] = pre[i] + hs[i];
            #pragma unroll
            for (int rr = 0; rr < 4; ++rr) {
                float box = pre[rr + 5] - pre[rr];
                float w = __expf(FSQRT(box) * minv_h);
                const int s2 = rbd + (rr + k) * RD;
                accR[rr] = fmaf(w, RGBL[s2], accR[rr]);
                accG[rr] = fmaf(w, RGBL[RSZ + s2], accG[rr]);
                accB[rr] = fmaf(w, RGBL[2 * RSZ + s2], accB[rr]);
                den[rr] += w;
            }
        }
    }

    #pragma unroll
    for (int rr = 0; rr < 4; ++rr) {
        int px = (ty0 + r0 + rr) * IW + tx0 + tx;
        float iw = 1.0f / den[rr];
        out[px]           = fminf(fmaxf(accR[rr] * iw, 0.f), 1.f);
        out[NPX + px]     = fminf(fmaxf(accG[rr] * iw, 0.f), 1.f);
        out[2 * NPX + px] = fminf(fmaxf(accB[rr] * iw, 0.f), 1.f);
    }
}

extern "C" void kernel_launch(void* const* d_in, const int* in_sizes, int n_in,
                              void* d_out, int out_size, void* d_ws, size_t ws_size,
                              hipStream_t stream) {
    const float* rgb   = (const float*)d_in[0];
    const float* sigma = (const float*)d_in[1];
    float* out = (float*)d_out;

    const size_t need6 = (size_t)6 * NPX * sizeof(float4);
    const size_t need4 = (size_t)4 * NPX * sizeof(float4);
    int nslice = (ws_size >= need6) ? 6 : (ws_size >= need4 ? 4 : 0);

    if (nslice > 0) {
        float4* ws = (float4*)d_ws;
        dim3 grid(NXT, IH / BH, nslice);   // 9 x 32 x {6|4}
        nlm_part<<<grid, dim3(256), 0, stream>>>(rgb, sigma, ws);
        nlm_combine<<<dim3(NPX / 256), dim3(256), 0, stream>>>(ws, out, nslice);
    } else {
        dim3 grid(IW / TS, IH / TS);
        nlm_mono<<<grid, dim3(256), 0, stream>>>(rgb, sigma, out);
    }
}

// Round 13
// 39.979 us; speedup vs baseline: 1.2120x; 1.0422x over previous
//
#include <hip/hip_runtime.h>
#include <math.h>

#define IH 512
#define IW 512
#define NPX (IH*IW)

// column-D + dpp-shift-box geometry
#define TW 60                // output columns per tile (64 lanes -> D cols -2..61)
#define BH 16                // tile height (4 waves x 4 rows)
#define NXT 9                // ceil(512/60)
#define YROWS 30             // image rows -7..22
#define YCOLS 74             // image cols -7..66
#define YSZ2 (YROWS*YCOLS)   // 2220 floats = 8880 B (ONLY LDS: occupancy lever)

// mono-fallback geometry (round-5 kernel)
#define TS 32
#define YHALO 7
#define RHALO 5
#define YD (TS + 2*YHALO)
#define RD (TS + 2*RHALO)
#define RSZ (RD*RD)
#define MYSZ (YD*YD)

#define FSQRT(x) __builtin_amdgcn_sqrtf(x)
#if __has_builtin(__builtin_amdgcn_exp2f)
#define FEXP2(x) __builtin_amdgcn_exp2f(x)
#else
#define FEXP2(x) exp2f(x)
#endif

// DPP wave_shl:1 (ctrl 0x130): lane i <- lane i+1, whole-wave, lane63 <- 0.
__device__ __forceinline__ float dpp_shl1(float x) {
    return __int_as_float(__builtin_amdgcn_update_dpp(
        0, __float_as_int(x), 0x130, 0xf, 0xf, true));
}

// ---------------- column-D compute kernel: dx-group per blockIdx.z -----------
// Round-12 post-mortem: part stuck at ~35us, VALUBusy 40%, Occupancy 23%
// (~2 waves/SIMD) -- dependency chains (prefix->dpp->sqrt->exp2, ~80cy/k)
// exposed by too few resident waves; 32KB LDS capped blocks/CU at 5 (~3
// achieved). This version: LDS = Y plane only (8.9KB); RGB read from GLOBAL
// (L1/L2-resident 3MB image) with rb[14] static row bases (regs) and 2-deep
// register prefetch (row k+5 loaded at k, consumed at k+2; vmcnt counter is
// independent of the Y lgkm reads). Staging halves. VGPR must stay <=104.
// NO min-waves clamp (round-2 lesson).
__global__ __launch_bounds__(256)
void nlm_part(const float* __restrict__ rgb,
              const float* __restrict__ sigma,
              float4* __restrict__ ws) {
    __shared__ float YL[YSZ2];

    const int tid   = threadIdx.x;
    const int lane  = tid & 63;
    const int wavei = tid >> 6;
    const int tx0 = blockIdx.x * TW;
    const int ty0 = blockIdx.y * BH;
    const int slice = blockIdx.z;
    const int nz = gridDim.z;

    const float* Rp = rgb;
    const float* Gp = rgb + NPX;
    const float* Bp = rgb + 2*NPX;

    // stage luminance: rows -7..22, cols -7..66 (circular)
    for (int idx = tid; idx < YSZ2; idx += 256) {
        int a = idx / YCOLS, b = idx - a*YCOLS;
        int gy = (ty0 + a - 7) & (IH-1);
        int gx = (tx0 + b - 7) & (IW-1);
        int g = gy*IW + gx;
        YL[idx] = 0.299f*Rp[g] + 0.587f*Gp[g] + 0.114f*Bp[g];
    }
    __syncthreads();

    const float m2 = -1.4426950408889634f /
                     (fmaxf(sigma[0]*2.0f, 0.0f) + 1e-6f);

    const int l  = lane;         // D col cd = l-2; output col = l (<60)
    const int r0 = wavei*4;      // strip start row

    // minuend Y at D col cd=l-2: rows r0-2..r0+5  (LDS: row r0+5+i, col l+5)
    float yb8[8];
    #pragma unroll
    for (int i = 0; i < 8; ++i)
        yb8[i] = YL[(r0+5+i)*YCOLS + (l+5)];

    // rgb row base offsets (element index, row<<9) for storage rows 0..13
    // (image rows ty0+r0-5 .. ty0+r0+8); static-indexed -> stays in registers
    int rb[14];
    #pragma unroll
    for (int q = 0; q < 14; ++q)
        rb[q] = ((ty0 + r0 - 5 + q) & (IH-1)) << 9;

    float accR[4]={0,0,0,0}, accG[4]={0,0,0,0},
          accB[4]={0,0,0,0}, den[4]={0,0,0,0};

    int dxlo, dxcnt;
    if (nz == 6) { if (slice < 5) { dxlo = -5 + 2*slice; dxcnt = 2; }
                   else           { dxlo = 5;            dxcnt = 1; } }
    else         { if (slice < 3) { dxlo = -5 + 3*slice; dxcnt = 3; }
                   else           { dxlo = 4;            dxcnt = 2; } }

    for (int u = 0; u < dxcnt; ++u) {
        const int dx = dxlo + u;
        const int ysb  = r0*YCOLS + (l + 5 - dx);     // Y subtrahend col base
        const int coli = (tx0 + l - dx) & (IW-1);     // rgb column (circular)

        // rolling Y subtrahend rows: slot j holds storage row j at k=0
        float sub8[8];
        #pragma unroll
        for (int j = 0; j < 8; ++j)
            sub8[j] = YL[ysb + j*YCOLS];
        float nY = YL[ysb + 8*YCOLS];                 // 1-deep Y prefetch

        // RGB window rows 0..3 in registers + 2-deep prefetch (rows 4,5)
        float rw[4], gw[4], bw[4];
        #pragma unroll
        for (int s = 0; s < 4; ++s) {
            int o = rb[s] + coli;
            rw[s] = Rp[o]; gw[s] = Gp[o]; bw[s] = Bp[o];
        }
        int oA = rb[4] + coli;
        float rA = Rp[oA], gA = Gp[oA], bA = Bp[oA];  // consume at k=1
        int oB = rb[5] + coli;
        float rB = Rp[oB], gB = Gp[oB], bB = Bp[oB];  // consume at k=2

        #pragma unroll
        for (int k = 0; k <= 10; ++k) {               // dy = 5 - k
            if (k > 0) {
                sub8[(k+7)&7] = nY;                   // Y row k+7
                if (k < 10) nY = YL[ysb + (8+k)*YCOLS];
                rw[(k+3)&3] = rA; gw[(k+3)&3] = gA; bw[(k+3)&3] = bA;
                rA = rB; gA = gB; bA = bB;            // renamed by unroll
                if (k <= 8) {                          // load row k+5
                    int o = rb[k+5] + coli;
                    rB = Rp[o]; gB = Gp[o]; bB = Bp[o];
                }
            }
            // own-column E + vertical box via prefix (square folded into fma)
            float pre[9]; pre[0] = 0.f;
            #pragma unroll
            for (int i = 0; i < 8; ++i) {
                float d = yb8[i] - sub8[(i+k)&7];
                pre[i+1] = fmaf(d, d, pre[i]);
            }
            float V[4];
            #pragma unroll
            for (int rr = 0; rr < 4; ++rr) V[rr] = pre[rr+5] - pre[rr];

            // horizontal 5-col box over lanes l..l+4 via chained dpp shifts
            float box[4];
            #pragma unroll
            for (int rr = 0; rr < 4; ++rr) {
                float s1 = dpp_shl1(V[rr]);           // V[l+1]
                float s2 = dpp_shl1(s1);              // V[l+2]
                float s3 = dpp_shl1(s2);              // V[l+3]
                float s4 = dpp_shl1(s3);              // V[l+4]
                box[rr] = ((V[rr] + s1) + (s2 + s3)) + s4;
            }
            #pragma unroll
            for (int rr = 0; rr < 4; ++rr) {
                float w = FEXP2(FSQRT(fmaxf(box[rr], 0.f)) * m2);
                accR[rr] = fmaf(w, rw[(k+rr)&3], accR[rr]);
                accG[rr] = fmaf(w, gw[(k+rr)&3], accG[rr]);
                accB[rr] = fmaf(w, bw[(k+rr)&3], accB[rr]);
                den[rr] += w;
            }
        }
    }

    if (l < TW && tx0 + l < IW) {
        #pragma unroll
        for (int rr = 0; rr < 4; ++rr) {
            int px = (ty0 + r0 + rr)*IW + tx0 + l;
            ws[(size_t)slice*NPX + px] =
                make_float4(accR[rr], accG[rr], accB[rr], den[rr]);
        }
    }
}

// ---------------- combine: sum nslice slices, normalize, clip ----------------
__global__ __launch_bounds__(256)
void nlm_combine(const float4* __restrict__ ws, float* __restrict__ out,
                 int nslice) {
    int px = blockIdx.x * 256 + threadIdx.x;
    float r = 0.f, g = 0.f, b = 0.f, w = 0.f;
    for (int s = 0; s < nslice; ++s) {
        float4 v = ws[(size_t)s * NPX + px];
        r += v.x; g += v.y; b += v.z; w += v.w;
    }
    float iw = 1.0f / w;
    out[px]           = fminf(fmaxf(r * iw, 0.f), 1.f);
    out[NPX + px]     = fminf(fmaxf(g * iw, 0.f), 1.f);
    out[2 * NPX + px] = fminf(fmaxf(b * iw, 0.f), 1.f);
}

// ---------------- fallback: round-5 monolithic kernel (ws too small) ---------
__global__ __launch_bounds__(256)
void nlm_mono(const float* __restrict__ rgb,
              const float* __restrict__ sigma,
              float* __restrict__ out) {
    __shared__ float Y[MYSZ];
    __shared__ float RGBL[3 * RSZ];

    const int tid = threadIdx.x;
    const int tx0 = blockIdx.x * TS;
    const int ty0 = blockIdx.y * TS;

    const float* Rp = rgb;
    const float* Gp = rgb + NPX;
    const float* Bp = rgb + 2 * NPX;

    for (int idx = tid; idx < MYSZ; idx += 256) {
        int a = idx / YD, b = idx - a * YD;
        int gy = (ty0 + a - YHALO) & (IH - 1);
        int gx = (tx0 + b - YHALO) & (IW - 1);
        int g = gy * IW + gx;
        Y[idx] = 0.299f * Rp[g] + 0.587f * Gp[g] + 0.114f * Bp[g];
    }
    for (int idx = tid; idx < RSZ; idx += 256) {
        int a = idx / RD, b = idx - a * RD;
        int gy = (ty0 + a - RHALO) & (IH - 1);
        int gx = (tx0 + b - RHALO) & (IW - 1);
        int g = gy * IW + gx;
        RGBL[idx]           = Rp[g];
        RGBL[RSZ + idx]     = Gp[g];
        RGBL[2 * RSZ + idx] = Bp[g];
    }
    __syncthreads();

    const float minv_h = -1.0f / (fmaxf(sigma[0] * 2.0f, 0.0f) + 1e-6f);
    const int tx = tid & 31;
    const int tz = tid >> 5;
    const int r0 = tz * 4;

    const int ybase = (YHALO + r0 - 2) * YD + (YHALO + tx - 2);
    float yb[8][5];
    #pragma unroll
    for (int i = 0; i < 8; ++i)
        #pragma unroll
        for (int b = 0; b < 5; ++b)
            yb[i][b] = Y[ybase + i * YD + b];

    float accR[4] = {0.f,0.f,0.f,0.f}, accG[4] = {0.f,0.f,0.f,0.f};
    float accB[4] = {0.f,0.f,0.f,0.f}, den[4] = {0.f,0.f,0.f,0.f};

    for (int dx = -5; dx <= 5; ++dx) {
        const int ybd = (YHALO + r0 - 7) * YD + (YHALO + tx - 2 - dx);
        const int rbd = (RHALO + r0 - 5) * RD + (RHALO + tx - dx);

        #pragma unroll
        for (int k = 0; k <= 10; ++k) {
            float hs[8];
            #pragma unroll
            for (int i = 0; i < 8; ++i) {
                float s = 0.f;
                #pragma unroll
                for (int b = 0; b < 5; ++b) {
                    float d = yb[i][b] - Y[ybd + (i + k) * YD + b];
                    s = fmaf(d, d, s);
                }
                hs[i] = s;
            }
            float pre[9];
            pre[0] = 0.f;
            #pragma unroll
            for (int i = 0; i < 8; ++i) pre[i + 1] = pre[i] + hs[i];
            #pragma unroll
            for (int rr = 0; rr < 4; ++rr) {
                float box = pre[rr + 5] - pre[rr];
                float w = __expf(FSQRT(box) * minv_h);
                const int s2 = rbd + (rr + k) * RD;
                accR[rr] = fmaf(w, RGBL[s2], accR[rr]);
                accG[rr] = fmaf(w, RGBL[RSZ + s2], accG[rr]);
                accB[rr] = fmaf(w, RGBL[2 * RSZ + s2], accB[rr]);
                den[rr] += w;
            }
        }
    }

    #pragma unroll
    for (int rr = 0; rr < 4; ++rr) {
        int px = (ty0 + r0 + rr) * IW + tx0 + tx;
        float iw = 1.0f / den[rr];
        out[px]           = fminf(fmaxf(accR[rr] * iw, 0.f), 1.f);
        out[NPX + px]     = fminf(fmaxf(accG[rr] * iw, 0.f), 1.f);
        out[2 * NPX + px] = fminf(fmaxf(accB[rr] * iw, 0.f), 1.f);
    }
}

extern "C" void kernel_launch(void* const* d_in, const int* in_sizes, int n_in,
                              void* d_out, int out_size, void* d_ws, size_t ws_size,
                              hipStream_t stream) {
    const float* rgb   = (const float*)d_in[0];
    const float* sigma = (const float*)d_in[1];
    float* out = (float*)d_out;

    const size_t need6 = (size_t)6 * NPX * sizeof(float4);
    const size_t need4 = (size_t)4 * NPX * sizeof(float4);
    int nslice = (ws_size >= need6) ? 6 : (ws_size >= need4 ? 4 : 0);

    if (nslice > 0) {
        float4* ws = (float4*)d_ws;
        dim3 grid(NXT, IH / BH, nslice);   // 9 x 32 x {6|4}
        nlm_part<<<grid, dim3(256), 0, stream>>>(rgb, sigma, ws);
        nlm_combine<<<dim3(NPX / 256), dim3(256), 0, stream>>>(ws, out, nslice);
    } else {
        dim3 grid(IW / TS, IH / TS);
        nlm_mono<<<grid, dim3(256), 0, stream>>>(rgb, sigma, out);
    }
}